// Round 8
// baseline (433.139 us; speedup 1.0000x reference)
//
#include <hip/hip_runtime.h>

#define FEAT 256
#define SEQ  2048
#define NBATCH 16

typedef float  f32x4  __attribute__((ext_vector_type(4)));
typedef __bf16 bf16x8 __attribute__((ext_vector_type(8)));

__device__ __forceinline__ unsigned short f2bf(float f) {
  union { float f; unsigned int u; } v; v.f = f;
  unsigned int r = (v.u + 0x7fffu + ((v.u >> 16) & 1u)) >> 16;
  return (unsigned short)r;
}
__device__ __forceinline__ float bf2f(unsigned short u) {
  union { unsigned int u; float f; } v; v.u = ((unsigned int)u) << 16;
  return v.f;
}
__device__ __forceinline__ unsigned int pack2bf(float a, float b) {
  // (bf16(a) | bf16(b)<<16)
  return (unsigned int)f2bf(a) | ((unsigned int)f2bf(b) << 16);
}

__device__ __forceinline__ float redsum16(float t) {
  t += __shfl_xor(t, 1);
  t += __shfl_xor(t, 2);
  t += __shfl_xor(t, 4);
  t += __shfl_xor(t, 8);
  return t;
}

// ---------------- kernel 0: convert weights fp32 -> bf16 ----------------
__global__ __launch_bounds__(256) void k_wcvt(
    const float* __restrict__ Wq, const float* __restrict__ Wk,
    const float* __restrict__ Wv, const float* __restrict__ W2,
    unsigned short* __restrict__ Wqb, unsigned short* __restrict__ Wkb,
    unsigned short* __restrict__ Wvb, unsigned short* __restrict__ W2b) {
  int i = blockIdx.x * 256 + threadIdx.x;  // 65536 total
  Wqb[i] = f2bf(Wq[i]);
  Wkb[i] = f2bf(Wk[i]);
  Wvb[i] = f2bf(Wv[i]);
  W2b[i] = f2bf(W2[i]);
}

// ---------------- kernel 1: h = x + posenc(p), bf16 out ----------------
__global__ __launch_bounds__(256) void k_pos_h(
    const float* __restrict__ x, const float* __restrict__ p,
    const float* __restrict__ W1, const float* __restrict__ b1,
    const unsigned short* __restrict__ W2b, const float* __restrict__ b2,
    unsigned short* __restrict__ hb) {
  __shared__ __align__(16) unsigned short tlds[64 * 264];
  __shared__ float pl[192];
  const int tid = threadIdx.x;
  const int blk = blockIdx.x;
  const int tok0 = blk * 64;
  if (tid < 192) pl[tid] = p[tok0 * 3 + tid];
  __syncthreads();
  // phase A: t = relu(p @ W1^T + b1), thread owns feature j = tid
  const int j = tid;
  const float w0 = W1[j * 3 + 0], w1 = W1[j * 3 + 1], w2 = W1[j * 3 + 2];
  const float bb = b1[j];
#pragma unroll 4
  for (int tl = 0; tl < 64; ++tl) {
    float v = bb + pl[tl * 3 + 0] * w0 + pl[tl * 3 + 1] * w1 + pl[tl * 3 + 2] * w2;
    v = v > 0.f ? v : 0.f;
    tlds[tl * 264 + j] = f2bf(v);
  }
  __syncthreads();
  // phase B: pos = t @ W2^T ; h = x + pos + b2
  const int w = tid >> 6, lane = tid & 63;
  const int col = lane & 15, quad = lane >> 4;
  bf16x8 af[8];
  const unsigned short* arow = tlds + (w * 16 + col) * 264 + quad * 8;
#pragma unroll
  for (int ks = 0; ks < 8; ++ks) af[ks] = *(const bf16x8*)(arow + ks * 32);
#pragma unroll 1
  for (int ct = 0; ct < 16; ++ct) {
    f32x4 acc = {0.f, 0.f, 0.f, 0.f};
    const unsigned short* brow = W2b + (ct * 16 + col) * 256 + quad * 8;
#pragma unroll
    for (int ks = 0; ks < 8; ++ks) {
      bf16x8 bf = *(const bf16x8*)(brow + ks * 32);
      acc = __builtin_amdgcn_mfma_f32_16x16x32_bf16(af[ks], bf, acc, 0, 0, 0);
    }
    const int f = ct * 16 + col;
    const float bias = b2[f];
#pragma unroll
    for (int r = 0; r < 4; ++r) {
      const int tok = tok0 + w * 16 + quad * 4 + r;
      float v = acc[r] + bias + x[tok * 256 + f];
      hb[tok * 256 + f] = f2bf(v);
    }
  }
}

// ---------------- kernel 2: q,k,v projections (note reference name swap!) ----
// q = h @ Wk^T + bk ; k = h @ Wq^T + bq ; v = h @ Wv^T + bv.
// v is stored transposed AND key-interleaved: within each 32-key group,
// storage index s(k) = 2*(k mod 16) + (k div 16). The quad owns keys
// t0..t0+3 (lo) and t0+16..t0+19 (hi) -> interleaved they form 8 CONTIGUOUS
// shorts = one 16B store (was two 8B stores).
__global__ __launch_bounds__(256) void k_qkv(
    const unsigned short* __restrict__ hb,
    const unsigned short* __restrict__ Wqb, const float* __restrict__ bq,
    const unsigned short* __restrict__ Wkb, const float* __restrict__ bk,
    const unsigned short* __restrict__ Wvb, const float* __restrict__ bv,
    unsigned short* __restrict__ qb, unsigned short* __restrict__ kb,
    unsigned short* __restrict__ vtb) {
  const int tid = threadIdx.x, blk = blockIdx.x;
  const int w = tid >> 6, lane = tid & 63;
  const int col = lane & 15, quad = lane >> 4;
  const int row0 = blk * 128 + w * 32;
  bf16x8 af0[8], af1[8];
  const unsigned short* arow0 = hb + (size_t)(row0 + col) * 256 + quad * 8;
  const unsigned short* arow1 = arow0 + 16 * 256;
#pragma unroll
  for (int ks = 0; ks < 8; ++ks) {
    af0[ks] = *(const bf16x8*)(arow0 + ks * 32);
    af1[ks] = *(const bf16x8*)(arow1 + ks * 32);
  }
#pragma unroll 1
  for (int mat = 0; mat < 3; ++mat) {
    const unsigned short* W = (mat == 0) ? Wkb : ((mat == 1) ? Wqb : Wvb);
    const float* bias = (mat == 0) ? bk : ((mat == 1) ? bq : bv);
#pragma unroll 1
    for (int ct = 0; ct < 16; ++ct) {
      f32x4 a0 = {0.f, 0.f, 0.f, 0.f}, a1 = {0.f, 0.f, 0.f, 0.f};
      const unsigned short* brow = W + (ct * 16 + col) * 256 + quad * 8;
#pragma unroll
      for (int ks = 0; ks < 8; ++ks) {
        bf16x8 bf = *(const bf16x8*)(brow + ks * 32);
        a0 = __builtin_amdgcn_mfma_f32_16x16x32_bf16(af0[ks], bf, a0, 0, 0, 0);
        a1 = __builtin_amdgcn_mfma_f32_16x16x32_bf16(af1[ks], bf, a1, 0, 0, 0);
      }
      const int f = ct * 16 + col;
      const float bs = bias[f];
      if (mat < 2) {
        unsigned short* dst = (mat == 0) ? qb : kb;
#pragma unroll
        for (int r = 0; r < 4; ++r) {
          dst[(size_t)(row0 + quad * 4 + r) * 256 + f] = f2bf(a0[r] + bs);
          dst[(size_t)(row0 + 16 + quad * 4 + r) * 256 + f] = f2bf(a1[r] + bs);
        }
      } else {
        // interleaved v store: shorts (a0[0],a1[0],a0[1],a1[1],...)
        uint4 pk;
        pk.x = pack2bf(a0[0] + bs, a1[0] + bs);
        pk.y = pack2bf(a0[1] + bs, a1[1] + bs);
        pk.z = pack2bf(a0[2] + bs, a1[2] + bs);
        pk.w = pack2bf(a0[3] + bs, a1[3] + bs);
        const int t0 = row0 + quad * 4;
        const int b0 = t0 >> 11, n = t0 & 2047;
        const int g = n >> 5, ki = n & 31;  // ki in {0,4,8,12} (< 16 by constr.)
        *(uint4*)(vtb + (size_t)(b0 * 256 + f) * 2048 + g * 32 + 2 * ki) = pk;
      }
    }
  }
}

// ---------------- kernel 3: flash attention, K-SPLIT x2 ----------------
// Round-7 A/B result: 2x waves/CU -> no change => shared per-CU throughput
// limit (LDS pipe + conflicts + staging latency). This round:
//  - P stored key-INTERLEAVED (s = 2*(k%16) + k/16): the lane's (p0,p1) pair
//    becomes one packed ds_write_b32 -> 8 b32 writes (2-way max, ~free)
//    instead of 16 b16 writes at 4-way conflict (the bulk of 1.1e7 cycles).
//    V is pre-interleaved identically by k_qkv, so the PV MFMA contracts in
//    s-order on both operands; all LDS READ addresses unchanged.
//  - Register-carried K/V prefetch (retry of round 5 w/o its failure modes:
//    VGPR budget has headroom at 128+32, clamped unconditional index).
//    Tripwire: WRITE_SIZE > 90 MB => spill => revert.
// Strides: Kl 264, Vt/Pl 40 -> all b128 reads conflict-free (bijection mod 8).
// Fixed-offset softmax; partials are pure sums; k_reduce combines halves.
// Epilogue fully unrolled (dynamic O index -> scratch demotion, rounds 1-2).
__global__ __launch_bounds__(256, 2) void k_attn(
    const unsigned short* __restrict__ qb, const unsigned short* __restrict__ kb,
    const unsigned short* __restrict__ vtb, float* __restrict__ outA,
    unsigned short* __restrict__ obB, float* __restrict__ lbuf) {
  __shared__ __align__(16) unsigned short Kl[32 * 264];    // [key][f]
  __shared__ __align__(16) unsigned short Vt[256 * 40];    // [f][s-key] pad 40
  __shared__ __align__(16) unsigned short Pl[4][32 * 40];  // [wave][row][s-key]
  const int tid = threadIdx.x;
  const int bx = blockIdx.x, b = blockIdx.y, h = blockIdx.z;
  const int w = tid >> 6, lane = tid & 63;
  const int col = lane & 15, quad = lane >> 4;
  const int n0 = bx * 128 + w * 32;
  const float scale = 0.0625f;  // 1/sqrt(256)

  bf16x8 qf0[8], qf1[8];
  const unsigned short* qrow0 = qb + (size_t)(b * 2048 + n0 + col) * 256 + quad * 8;
  const unsigned short* qrow1 = qrow0 + 16 * 256;
#pragma unroll
  for (int ks = 0; ks < 8; ++ks) {
    qf0[ks] = *(const bf16x8*)(qrow0 + ks * 32);
    qf1[ks] = *(const bf16x8*)(qrow1 + ks * 32);
  }

  f32x4 O0[16], O1[16];
#pragma unroll
  for (int ft = 0; ft < 16; ++ft) {
    O0[ft] = (f32x4){0.f, 0.f, 0.f, 0.f};
    O1[ft] = (f32x4){0.f, 0.f, 0.f, 0.f};
  }
  float ls0[4], ls1[4];
#pragma unroll
  for (int r = 0; r < 4; ++r) { ls0[r] = 0.f; ls1[r] = 0.f; }

  const uint4* ksrc = (const uint4*)(kb) + (size_t)b * 2048 * 32;  // [row][c:32]
  const uint4* vsrc = (const uint4*)(vtb);  // [(b*256+f)*256 + kt*4 + cc]
  unsigned short* Pw = Pl[w];
  const int kt0 = h * 32;

  // prefetch tile kt0 into registers (NOT loop-carried conditionals)
  uint4 kreg[4], vreg[4];
#pragma unroll
  for (int pp = 0; pp < 4; ++pp) {
    const int idx = pp * 256 + tid;
    const int r = idx >> 5, c = idx & 31;
    kreg[pp] = ksrc[(size_t)(kt0 * 32 + r) * 32 + c];
    const int f = idx >> 2, cc = idx & 3;
    vreg[pp] = vsrc[(size_t)(b * 256 + f) * 256 + kt0 * 4 + cc];
  }

  for (int kt2 = 0; kt2 < 32; ++kt2) {
    const int kt = kt0 + kt2;
    __syncthreads();  // all waves done reading K/V LDS of prev iter
    // write prefetched tile kt into LDS (vmcnt drain lands here)
#pragma unroll
    for (int pp = 0; pp < 4; ++pp) {
      const int idx = pp * 256 + tid;
      const int r = idx >> 5, c = idx & 31;
      *(uint4*)(Kl + r * 264 + c * 8) = kreg[pp];
      const int f = idx >> 2, cc = idx & 3;
      *(uint4*)(Vt + f * 40 + cc * 8) = vreg[pp];
    }
    __syncthreads();  // LDS tile ready
    // issue loads for next tile (clamped index: unconditional defs, last tile
    // re-loads itself harmlessly); they stay in flight across compute.
    {
      const int ktn = kt0 + (kt2 + 1 < 32 ? kt2 + 1 : 31);
#pragma unroll
      for (int pp = 0; pp < 4; ++pp) {
        const int idx = pp * 256 + tid;
        const int r = idx >> 5, c = idx & 31;
        kreg[pp] = ksrc[(size_t)(ktn * 32 + r) * 32 + c];
        const int f = idx >> 2, cc = idx & 3;
        vreg[pp] = vsrc[(size_t)(b * 256 + f) * 256 + ktn * 4 + cc];
      }
    }
    // S = q @ k^T : 2 row-frags x 2 key-tiles; K-frags shared across row-frags
    f32x4 s00 = {0.f, 0.f, 0.f, 0.f}, s01 = {0.f, 0.f, 0.f, 0.f};
    f32x4 s10 = {0.f, 0.f, 0.f, 0.f}, s11 = {0.f, 0.f, 0.f, 0.f};
#pragma unroll
    for (int ks = 0; ks < 8; ++ks) {
      bf16x8 k0 = *(const bf16x8*)(Kl + col * 264 + ks * 32 + quad * 8);
      bf16x8 k1 = *(const bf16x8*)(Kl + (16 + col) * 264 + ks * 32 + quad * 8);
      s00 = __builtin_amdgcn_mfma_f32_16x16x32_bf16(qf0[ks], k0, s00, 0, 0, 0);
      s01 = __builtin_amdgcn_mfma_f32_16x16x32_bf16(qf0[ks], k1, s01, 0, 0, 0);
      s10 = __builtin_amdgcn_mfma_f32_16x16x32_bf16(qf1[ks], k0, s10, 0, 0, 0);
      s11 = __builtin_amdgcn_mfma_f32_16x16x32_bf16(qf1[ks], k1, s11, 0, 0, 0);
    }
    // fixed-offset exp; lane-local l accumulation; packed P -> per-wave LDS.
    // s00[r] is key=col (s-pos 2*col), s01[r] key=col+16 (s-pos 2*col+1):
    // adjacent under interleave -> ONE b32 write per (row,frag).
#pragma unroll
    for (int r = 0; r < 4; ++r) {
      float p0 = __expf(fmaf(s00[r], scale, -8.0f));
      float p1 = __expf(fmaf(s01[r], scale, -8.0f));
      ls0[r] += p0 + p1;
      *(unsigned int*)(Pw + (quad * 4 + r) * 40 + 2 * col) = pack2bf(p0, p1);
      float q0 = __expf(fmaf(s10[r], scale, -8.0f));
      float q1 = __expf(fmaf(s11[r], scale, -8.0f));
      ls1[r] += q0 + q1;
      *(unsigned int*)(Pw + (16 + quad * 4 + r) * 40 + 2 * col) = pack2bf(q0, q1);
    }
    // NO barrier: Pl[w] is per-wave; same-wave LDS RAW ordered by lgkmcnt.
    bf16x8 pf0 = *(const bf16x8*)(Pw + col * 40 + quad * 8);
    bf16x8 pf1 = *(const bf16x8*)(Pw + (16 + col) * 40 + quad * 8);
    // PV: O += P @ V ; V-frags shared across row-frags (s-order both sides)
#pragma unroll
    for (int ft = 0; ft < 16; ++ft) {
      bf16x8 vf = *(const bf16x8*)(Vt + (ft * 16 + col) * 40 + quad * 8);
      O0[ft] = __builtin_amdgcn_mfma_f32_16x16x32_bf16(pf0, vf, O0[ft], 0, 0, 0);
      O1[ft] = __builtin_amdgcn_mfma_f32_16x16x32_bf16(pf1, vf, O1[ft], 0, 0, 0);
    }
  }
  // epilogue: write UNDIVIDED partial O and partial l (FULLY UNROLLED).
  float sr0[4], sr1[4];
#pragma unroll
  for (int r = 0; r < 4; ++r) {
    sr0[r] = redsum16(ls0[r]);
    sr1[r] = redsum16(ls1[r]);
  }
  if (h == 0) {
    if (col == 0) {
#pragma unroll
      for (int r = 0; r < 4; ++r) {
        lbuf[b * 2048 + n0 + quad * 4 + r] = sr0[r];
        lbuf[b * 2048 + n0 + 16 + quad * 4 + r] = sr1[r];
      }
    }
#pragma unroll
    for (int ft = 0; ft < 16; ++ft) {
#pragma unroll
      for (int r = 0; r < 4; ++r) {
        const int n = n0 + quad * 4 + r;
        outA[(size_t)(b * 2048 + n) * 256 + ft * 16 + col] = O0[ft][r];
        outA[(size_t)(b * 2048 + n + 16) * 256 + ft * 16 + col] = O1[ft][r];
      }
    }
  } else {
    if (col == 0) {
#pragma unroll
      for (int r = 0; r < 4; ++r) {
        lbuf[32768 + b * 2048 + n0 + quad * 4 + r] = sr0[r];
        lbuf[32768 + b * 2048 + n0 + 16 + quad * 4 + r] = sr1[r];
      }
    }
#pragma unroll
    for (int ft = 0; ft < 16; ++ft) {
#pragma unroll
      for (int r = 0; r < 4; ++r) {
        const int n = n0 + quad * 4 + r;
        obB[(size_t)(b * 2048 + n) * 256 + ft * 16 + col] = f2bf(O0[ft][r]);
        obB[(size_t)(b * 2048 + n + 16) * 256 + ft * 16 + col] = f2bf(O1[ft][r]);
      }
    }
  }
}

// ---------------- kernel 4: combine K-split partials ----------------
// out = (Oa + Ob) / (la + lb); Oa fp32 in d_out (in-place), Ob bf16.
__global__ __launch_bounds__(256) void k_reduce(
    float* __restrict__ out, const unsigned short* __restrict__ ob,
    const float* __restrict__ lbuf) {
  const size_t i4 = (size_t)blockIdx.x * 256 + threadIdx.x;  // 2M float4's
  const int bn = (int)(i4 >> 6);
  const float rl = 1.0f / (lbuf[bn] + lbuf[32768 + bn]);
  float4 o = ((const float4*)out)[i4];
  ushort4 b4 = ((const ushort4*)ob)[i4];
  o.x = (o.x + bf2f(b4.x)) * rl;
  o.y = (o.y + bf2f(b4.y)) * rl;
  o.z = (o.z + bf2f(b4.z)) * rl;
  o.w = (o.w + bf2f(b4.w)) * rl;
  ((float4*)out)[i4] = o;
}

// ---------------- launcher ----------------
extern "C" void kernel_launch(void* const* d_in, const int* in_sizes, int n_in,
                              void* d_out, int out_size, void* d_ws, size_t ws_size,
                              hipStream_t stream) {
  const float* x  = (const float*)d_in[0];
  const float* p  = (const float*)d_in[1];
  const float* Wq = (const float*)d_in[2];
  const float* bq = (const float*)d_in[3];
  const float* Wk = (const float*)d_in[4];
  const float* bk = (const float*)d_in[5];
  const float* Wv = (const float*)d_in[6];
  const float* bv = (const float*)d_in[7];
  const float* W1 = (const float*)d_in[8];
  const float* b1 = (const float*)d_in[9];
  const float* W2 = (const float*)d_in[10];
  const float* b2 = (const float*)d_in[11];
  float* out = (float*)d_out;

  char* ws = (char*)d_ws;
  unsigned short* W2b = (unsigned short*)(ws + 0);
  unsigned short* Wqb = (unsigned short*)(ws + 131072);
  unsigned short* Wkb = (unsigned short*)(ws + 262144);
  unsigned short* Wvb = (unsigned short*)(ws + 393216);
  unsigned short* hb  = (unsigned short*)(ws + 524288);            // 16 MB
  unsigned short* qb  = (unsigned short*)(ws + 524288 + 16777216);
  unsigned short* kb  = (unsigned short*)(ws + 524288 + 2 * 16777216);
  unsigned short* vtb = (unsigned short*)(ws + 524288 + 3 * 16777216);
  float* lbuf = (float*)(ws + 524288 + 4 * 16777216);              // 256 KB
  // hb is dead after k_qkv -> reused as the half-1 bf16 partial (obB).
  // total ws use: 524288 + 4*16777216 + 262144 = 67,895,296 bytes

  k_wcvt<<<256, 256, 0, stream>>>(Wq, Wk, Wv, W2, Wqb, Wkb, Wvb, W2b);
  k_pos_h<<<512, 256, 0, stream>>>(x, p, W1, b1, W2b, b2, hb);
  k_qkv<<<256, 256, 0, stream>>>(hb, Wqb, bq, Wkb, bk, Wvb, bv, qb, kb, vtb);
  k_attn<<<dim3(16, 16, 2), 256, 0, stream>>>(qb, kb, vtb, out, hb, lbuf);
  k_reduce<<<8192, 256, 0, stream>>>(out, hb, lbuf);
}

// Round 9
// 327.878 us; speedup vs baseline: 1.3210x; 1.3210x over previous
//
#include <hip/hip_runtime.h>

#define FEAT 256
#define SEQ  2048
#define NBATCH 16

typedef float  f32x4  __attribute__((ext_vector_type(4)));
typedef __bf16 bf16x8 __attribute__((ext_vector_type(8)));

__device__ __forceinline__ unsigned short f2bf(float f) {
  union { float f; unsigned int u; } v; v.f = f;
  unsigned int r = (v.u + 0x7fffu + ((v.u >> 16) & 1u)) >> 16;
  return (unsigned short)r;
}
__device__ __forceinline__ float bf2f(unsigned short u) {
  union { unsigned int u; float f; } v; v.u = ((unsigned int)u) << 16;
  return v.f;
}
__device__ __forceinline__ unsigned int pack2bf(float a, float b) {
  return (unsigned int)f2bf(a) | ((unsigned int)f2bf(b) << 16);
}

__device__ __forceinline__ float redsum16(float t) {
  t += __shfl_xor(t, 1);
  t += __shfl_xor(t, 2);
  t += __shfl_xor(t, 4);
  t += __shfl_xor(t, 8);
  return t;
}

// ---------------- kernel 0: convert weights fp32 -> bf16 ----------------
__global__ __launch_bounds__(256) void k_wcvt(
    const float* __restrict__ Wq, const float* __restrict__ Wk,
    const float* __restrict__ Wv, const float* __restrict__ W2,
    unsigned short* __restrict__ Wqb, unsigned short* __restrict__ Wkb,
    unsigned short* __restrict__ Wvb, unsigned short* __restrict__ W2b) {
  int i = blockIdx.x * 256 + threadIdx.x;  // 65536 total
  Wqb[i] = f2bf(Wq[i]);
  Wkb[i] = f2bf(Wk[i]);
  Wvb[i] = f2bf(Wv[i]);
  W2b[i] = f2bf(W2[i]);
}

// ---------------- kernel 1: h = x + posenc(p), bf16 out ----------------
__global__ __launch_bounds__(256) void k_pos_h(
    const float* __restrict__ x, const float* __restrict__ p,
    const float* __restrict__ W1, const float* __restrict__ b1,
    const unsigned short* __restrict__ W2b, const float* __restrict__ b2,
    unsigned short* __restrict__ hb) {
  __shared__ __align__(16) unsigned short tlds[64 * 264];
  __shared__ float pl[192];
  const int tid = threadIdx.x;
  const int blk = blockIdx.x;
  const int tok0 = blk * 64;
  if (tid < 192) pl[tid] = p[tok0 * 3 + tid];
  __syncthreads();
  // phase A: t = relu(p @ W1^T + b1), thread owns feature j = tid
  const int j = tid;
  const float w0 = W1[j * 3 + 0], w1 = W1[j * 3 + 1], w2 = W1[j * 3 + 2];
  const float bb = b1[j];
#pragma unroll 4
  for (int tl = 0; tl < 64; ++tl) {
    float v = bb + pl[tl * 3 + 0] * w0 + pl[tl * 3 + 1] * w1 + pl[tl * 3 + 2] * w2;
    v = v > 0.f ? v : 0.f;
    tlds[tl * 264 + j] = f2bf(v);
  }
  __syncthreads();
  // phase B: pos = t @ W2^T ; h = x + pos + b2
  const int w = tid >> 6, lane = tid & 63;
  const int col = lane & 15, quad = lane >> 4;
  bf16x8 af[8];
  const unsigned short* arow = tlds + (w * 16 + col) * 264 + quad * 8;
#pragma unroll
  for (int ks = 0; ks < 8; ++ks) af[ks] = *(const bf16x8*)(arow + ks * 32);
#pragma unroll 1
  for (int ct = 0; ct < 16; ++ct) {
    f32x4 acc = {0.f, 0.f, 0.f, 0.f};
    const unsigned short* brow = W2b + (ct * 16 + col) * 256 + quad * 8;
#pragma unroll
    for (int ks = 0; ks < 8; ++ks) {
      bf16x8 bf = *(const bf16x8*)(brow + ks * 32);
      acc = __builtin_amdgcn_mfma_f32_16x16x32_bf16(af[ks], bf, acc, 0, 0, 0);
    }
    const int f = ct * 16 + col;
    const float bias = b2[f];
#pragma unroll
    for (int r = 0; r < 4; ++r) {
      const int tok = tok0 + w * 16 + quad * 4 + r;
      float v = acc[r] + bias + x[tok * 256 + f];
      hb[tok * 256 + f] = f2bf(v);
    }
  }
}

// ---------------- kernel 2: q,k,v projections (note reference name swap!) ----
// q = h @ Wk^T + bk ; k = h @ Wq^T + bq ; v = h @ Wv^T + bv.
// Round-9: grid (256,2) — blockIdx.y picks an 8-wide ct half (output cols
// 128*half..128*half+127). 512 blocks = 2 blocks/CU = 2 waves/SIMD (was 1:
// the round-6-diagnosed starvation). A-frag reuse (32 rows/wave) kept;
// weight rows now read 2x but are L2-resident.
// v stored transposed AND key-interleaved: s(k) = 2*(k%16) + k/16 within each
// 32-key group -> quad's lo/hi key pairs are contiguous: one 16B store.
__global__ __launch_bounds__(256) void k_qkv(
    const unsigned short* __restrict__ hb,
    const unsigned short* __restrict__ Wqb, const float* __restrict__ bq,
    const unsigned short* __restrict__ Wkb, const float* __restrict__ bk,
    const unsigned short* __restrict__ Wvb, const float* __restrict__ bv,
    unsigned short* __restrict__ qb, unsigned short* __restrict__ kb,
    unsigned short* __restrict__ vtb) {
  const int tid = threadIdx.x, blk = blockIdx.x;
  const int ct0 = blockIdx.y * 8;
  const int w = tid >> 6, lane = tid & 63;
  const int col = lane & 15, quad = lane >> 4;
  const int row0 = blk * 128 + w * 32;
  bf16x8 af0[8], af1[8];
  const unsigned short* arow0 = hb + (size_t)(row0 + col) * 256 + quad * 8;
  const unsigned short* arow1 = arow0 + 16 * 256;
#pragma unroll
  for (int ks = 0; ks < 8; ++ks) {
    af0[ks] = *(const bf16x8*)(arow0 + ks * 32);
    af1[ks] = *(const bf16x8*)(arow1 + ks * 32);
  }
#pragma unroll 1
  for (int mat = 0; mat < 3; ++mat) {
    const unsigned short* W = (mat == 0) ? Wkb : ((mat == 1) ? Wqb : Wvb);
    const float* bias = (mat == 0) ? bk : ((mat == 1) ? bq : bv);
#pragma unroll 1
    for (int ct = ct0; ct < ct0 + 8; ++ct) {
      f32x4 a0 = {0.f, 0.f, 0.f, 0.f}, a1 = {0.f, 0.f, 0.f, 0.f};
      const unsigned short* brow = W + (ct * 16 + col) * 256 + quad * 8;
#pragma unroll
      for (int ks = 0; ks < 8; ++ks) {
        bf16x8 bf = *(const bf16x8*)(brow + ks * 32);
        a0 = __builtin_amdgcn_mfma_f32_16x16x32_bf16(af0[ks], bf, a0, 0, 0, 0);
        a1 = __builtin_amdgcn_mfma_f32_16x16x32_bf16(af1[ks], bf, a1, 0, 0, 0);
      }
      const int f = ct * 16 + col;
      const float bs = bias[f];
      if (mat < 2) {
        unsigned short* dst = (mat == 0) ? qb : kb;
#pragma unroll
        for (int r = 0; r < 4; ++r) {
          dst[(size_t)(row0 + quad * 4 + r) * 256 + f] = f2bf(a0[r] + bs);
          dst[(size_t)(row0 + 16 + quad * 4 + r) * 256 + f] = f2bf(a1[r] + bs);
        }
      } else {
        // interleaved v store: shorts (a0[0],a1[0],a0[1],a1[1],...)
        uint4 pk;
        pk.x = pack2bf(a0[0] + bs, a1[0] + bs);
        pk.y = pack2bf(a0[1] + bs, a1[1] + bs);
        pk.z = pack2bf(a0[2] + bs, a1[2] + bs);
        pk.w = pack2bf(a0[3] + bs, a1[3] + bs);
        const int t0 = row0 + quad * 4;
        const int b0 = t0 >> 11, n = t0 & 2047;
        const int g = n >> 5, ki = n & 31;  // ki in {0,4,8,12}
        *(uint4*)(vtb + (size_t)(b0 * 256 + f) * 2048 + g * 32 + 2 * ki) = pk;
      }
    }
  }
}

// ---------------- kernel 3: flash attention, K-SPLIT x2 ----------------
// REVERTED to the round-7-measured structure (138.8 us): NO register-carried
// prefetch. Twice-confirmed (rounds 5, 8): the compiler spills loop-carried
// staging registers across the MFMA body (WRITE_SIZE 117MB / 558MB) rather
// than exceed its VGPR heuristic. Plain stage->barrier->compute.
// P stored key-interleaved (packed ds_write_b32); V pre-interleaved by k_qkv.
// (Conflict counter was bit-identical across P-format changes -> P-writes are
// not the conflict source; 1.1e7 cyc ~ 13% of wall, not the main lever.)
// Fixed-offset softmax; partials pure sums; k_reduce combines halves.
// Epilogue fully unrolled (dynamic O index -> scratch demotion, rounds 1-2).
__global__ __launch_bounds__(256, 2) void k_attn(
    const unsigned short* __restrict__ qb, const unsigned short* __restrict__ kb,
    const unsigned short* __restrict__ vtb, float* __restrict__ outA,
    unsigned short* __restrict__ obB, float* __restrict__ lbuf) {
  __shared__ __align__(16) unsigned short Kl[32 * 264];    // [key][f]
  __shared__ __align__(16) unsigned short Vt[256 * 40];    // [f][s-key] pad 40
  __shared__ __align__(16) unsigned short Pl[4][32 * 40];  // [wave][row][s-key]
  const int tid = threadIdx.x;
  const int bx = blockIdx.x, b = blockIdx.y, h = blockIdx.z;
  const int w = tid >> 6, lane = tid & 63;
  const int col = lane & 15, quad = lane >> 4;
  const int n0 = bx * 128 + w * 32;
  const float scale = 0.0625f;  // 1/sqrt(256)

  bf16x8 qf0[8], qf1[8];
  const unsigned short* qrow0 = qb + (size_t)(b * 2048 + n0 + col) * 256 + quad * 8;
  const unsigned short* qrow1 = qrow0 + 16 * 256;
#pragma unroll
  for (int ks = 0; ks < 8; ++ks) {
    qf0[ks] = *(const bf16x8*)(qrow0 + ks * 32);
    qf1[ks] = *(const bf16x8*)(qrow1 + ks * 32);
  }

  f32x4 O0[16], O1[16];
#pragma unroll
  for (int ft = 0; ft < 16; ++ft) {
    O0[ft] = (f32x4){0.f, 0.f, 0.f, 0.f};
    O1[ft] = (f32x4){0.f, 0.f, 0.f, 0.f};
  }
  float ls0[4], ls1[4];
#pragma unroll
  for (int r = 0; r < 4; ++r) { ls0[r] = 0.f; ls1[r] = 0.f; }

  const uint4* ksrc = (const uint4*)(kb) + (size_t)b * 2048 * 32;  // [row][c:32]
  const uint4* vsrc = (const uint4*)(vtb);  // [(b*256+f)*256 + kt*4 + cc]
  unsigned short* Pw = Pl[w];
  const int kt0 = h * 32;

  for (int kt2 = 0; kt2 < 32; ++kt2) {
    const int kt = kt0 + kt2;
    __syncthreads();  // all waves done reading K/V LDS of prev iter
    {  // stage K tile [32][256] and V^T tile [256][32] (transient registers)
#pragma unroll
      for (int pp = 0; pp < 4; ++pp) {
        const int idx = pp * 256 + tid;
        const int r = idx >> 5, c = idx & 31;
        *(uint4*)(Kl + r * 264 + c * 8) = ksrc[(size_t)(kt * 32 + r) * 32 + c];
        const int f = idx >> 2, cc = idx & 3;
        *(uint4*)(Vt + f * 40 + cc * 8) =
            vsrc[(size_t)(b * 256 + f) * 256 + kt * 4 + cc];
      }
    }
    __syncthreads();  // LDS tile ready
    // S = q @ k^T : 2 row-frags x 2 key-tiles; K-frags shared across row-frags
    f32x4 s00 = {0.f, 0.f, 0.f, 0.f}, s01 = {0.f, 0.f, 0.f, 0.f};
    f32x4 s10 = {0.f, 0.f, 0.f, 0.f}, s11 = {0.f, 0.f, 0.f, 0.f};
#pragma unroll
    for (int ks = 0; ks < 8; ++ks) {
      bf16x8 k0 = *(const bf16x8*)(Kl + col * 264 + ks * 32 + quad * 8);
      bf16x8 k1 = *(const bf16x8*)(Kl + (16 + col) * 264 + ks * 32 + quad * 8);
      s00 = __builtin_amdgcn_mfma_f32_16x16x32_bf16(qf0[ks], k0, s00, 0, 0, 0);
      s01 = __builtin_amdgcn_mfma_f32_16x16x32_bf16(qf0[ks], k1, s01, 0, 0, 0);
      s10 = __builtin_amdgcn_mfma_f32_16x16x32_bf16(qf1[ks], k0, s10, 0, 0, 0);
      s11 = __builtin_amdgcn_mfma_f32_16x16x32_bf16(qf1[ks], k1, s11, 0, 0, 0);
    }
    // fixed-offset exp; lane-local l accumulation; packed P -> per-wave LDS.
    // s00[r] = key col (s-pos 2*col), s01[r] = key col+16 (s-pos 2*col+1):
    // adjacent under interleave -> ONE b32 write per (row,frag).
#pragma unroll
    for (int r = 0; r < 4; ++r) {
      float p0 = __expf(fmaf(s00[r], scale, -8.0f));
      float p1 = __expf(fmaf(s01[r], scale, -8.0f));
      ls0[r] += p0 + p1;
      *(unsigned int*)(Pw + (quad * 4 + r) * 40 + 2 * col) = pack2bf(p0, p1);
      float q0 = __expf(fmaf(s10[r], scale, -8.0f));
      float q1 = __expf(fmaf(s11[r], scale, -8.0f));
      ls1[r] += q0 + q1;
      *(unsigned int*)(Pw + (16 + quad * 4 + r) * 40 + 2 * col) = pack2bf(q0, q1);
    }
    // NO barrier: Pl[w] is per-wave; same-wave LDS RAW ordered by lgkmcnt.
    bf16x8 pf0 = *(const bf16x8*)(Pw + col * 40 + quad * 8);
    bf16x8 pf1 = *(const bf16x8*)(Pw + (16 + col) * 40 + quad * 8);
    // PV: O += P @ V ; V-frags shared across row-frags (s-order both sides)
#pragma unroll
    for (int ft = 0; ft < 16; ++ft) {
      bf16x8 vf = *(const bf16x8*)(Vt + (ft * 16 + col) * 40 + quad * 8);
      O0[ft] = __builtin_amdgcn_mfma_f32_16x16x32_bf16(pf0, vf, O0[ft], 0, 0, 0);
      O1[ft] = __builtin_amdgcn_mfma_f32_16x16x32_bf16(pf1, vf, O1[ft], 0, 0, 0);
    }
  }
  // epilogue: write UNDIVIDED partial O and partial l (FULLY UNROLLED).
  float sr0[4], sr1[4];
#pragma unroll
  for (int r = 0; r < 4; ++r) {
    sr0[r] = redsum16(ls0[r]);
    sr1[r] = redsum16(ls1[r]);
  }
  if (h == 0) {
    if (col == 0) {
#pragma unroll
      for (int r = 0; r < 4; ++r) {
        lbuf[b * 2048 + n0 + quad * 4 + r] = sr0[r];
        lbuf[b * 2048 + n0 + 16 + quad * 4 + r] = sr1[r];
      }
    }
#pragma unroll
    for (int ft = 0; ft < 16; ++ft) {
#pragma unroll
      for (int r = 0; r < 4; ++r) {
        const int n = n0 + quad * 4 + r;
        outA[(size_t)(b * 2048 + n) * 256 + ft * 16 + col] = O0[ft][r];
        outA[(size_t)(b * 2048 + n + 16) * 256 + ft * 16 + col] = O1[ft][r];
      }
    }
  } else {
    if (col == 0) {
#pragma unroll
      for (int r = 0; r < 4; ++r) {
        lbuf[32768 + b * 2048 + n0 + quad * 4 + r] = sr0[r];
        lbuf[32768 + b * 2048 + n0 + 16 + quad * 4 + r] = sr1[r];
      }
    }
#pragma unroll
    for (int ft = 0; ft < 16; ++ft) {
#pragma unroll
      for (int r = 0; r < 4; ++r) {
        const int n = n0 + quad * 4 + r;
        obB[(size_t)(b * 2048 + n) * 256 + ft * 16 + col] = f2bf(O0[ft][r]);
        obB[(size_t)(b * 2048 + n + 16) * 256 + ft * 16 + col] = f2bf(O1[ft][r]);
      }
    }
  }
}

// ---------------- kernel 4: combine K-split partials ----------------
// out = (Oa + Ob) / (la + lb); Oa fp32 in d_out (in-place), Ob bf16.
__global__ __launch_bounds__(256) void k_reduce(
    float* __restrict__ out, const unsigned short* __restrict__ ob,
    const float* __restrict__ lbuf) {
  const size_t i4 = (size_t)blockIdx.x * 256 + threadIdx.x;  // 2M float4's
  const int bn = (int)(i4 >> 6);
  const float rl = 1.0f / (lbuf[bn] + lbuf[32768 + bn]);
  float4 o = ((const float4*)out)[i4];
  ushort4 b4 = ((const ushort4*)ob)[i4];
  o.x = (o.x + bf2f(b4.x)) * rl;
  o.y = (o.y + bf2f(b4.y)) * rl;
  o.z = (o.z + bf2f(b4.z)) * rl;
  o.w = (o.w + bf2f(b4.w)) * rl;
  ((float4*)out)[i4] = o;
}

// ---------------- launcher ----------------
extern "C" void kernel_launch(void* const* d_in, const int* in_sizes, int n_in,
                              void* d_out, int out_size, void* d_ws, size_t ws_size,
                              hipStream_t stream) {
  const float* x  = (const float*)d_in[0];
  const float* p  = (const float*)d_in[1];
  const float* Wq = (const float*)d_in[2];
  const float* bq = (const float*)d_in[3];
  const float* Wk = (const float*)d_in[4];
  const float* bk = (const float*)d_in[5];
  const float* Wv = (const float*)d_in[6];
  const float* bv = (const float*)d_in[7];
  const float* W1 = (const float*)d_in[8];
  const float* b1 = (const float*)d_in[9];
  const float* W2 = (const float*)d_in[10];
  const float* b2 = (const float*)d_in[11];
  float* out = (float*)d_out;

  char* ws = (char*)d_ws;
  unsigned short* W2b = (unsigned short*)(ws + 0);
  unsigned short* Wqb = (unsigned short*)(ws + 131072);
  unsigned short* Wkb = (unsigned short*)(ws + 262144);
  unsigned short* Wvb = (unsigned short*)(ws + 393216);
  unsigned short* hb  = (unsigned short*)(ws + 524288);            // 16 MB
  unsigned short* qb  = (unsigned short*)(ws + 524288 + 16777216);
  unsigned short* kb  = (unsigned short*)(ws + 524288 + 2 * 16777216);
  unsigned short* vtb = (unsigned short*)(ws + 524288 + 3 * 16777216);
  float* lbuf = (float*)(ws + 524288 + 4 * 16777216);              // 256 KB
  // hb is dead after k_qkv -> reused as the half-1 bf16 partial (obB).
  // total ws use: 524288 + 4*16777216 + 262144 = 67,895,296 bytes

  k_wcvt<<<256, 256, 0, stream>>>(Wq, Wk, Wv, W2, Wqb, Wkb, Wvb, W2b);
  k_pos_h<<<512, 256, 0, stream>>>(x, p, W1, b1, W2b, b2, hb);
  k_qkv<<<dim3(256, 2), 256, 0, stream>>>(hb, Wqb, bq, Wkb, bk, Wvb, bv, qb, kb, vtb);
  k_attn<<<dim3(16, 16, 2), 256, 0, stream>>>(qb, kb, vtb, out, hb, lbuf);
  k_reduce<<<8192, 256, 0, stream>>>(out, hb, lbuf);
}